// Round 18
// baseline (190.066 us; speedup 1.0000x reference)
//
#include <hip/hip_runtime.h>
#include <hip/hip_bf16.h>

static constexpr int S_    = 2048;
static constexpr int D_    = 2048;
static constexpr int NH_   = 32;
static constexpr int NKVH_ = 8;
static constexpr int HD_   = 64;
static constexpr int KVD_  = NKVH_ * HD_;   // 512
static constexpr int NQKV_ = 3288;          // 2048 q + 512 k + 512 v + 192 H + 24 logits
static constexpr int NOUT_ = 2120;          // 2048 o + 64 H + 8 logits

using bf16 = __hip_bfloat16;
typedef __attribute__((ext_vector_type(4))) float f32x4;
typedef __attribute__((ext_vector_type(8))) short s16x8;

__device__ inline unsigned short f2bf_bits(float f) {
  bf16 h = __float2bfloat16(f);
  union { bf16 b; unsigned short u; } cv; cv.b = h; return cv.u;
}
__device__ inline float bfbits2f(unsigned short u) {
  union { unsigned u32; float f; } cv; cv.u32 = (unsigned)u << 16; return cv.f;
}
__device__ inline float fexp2(float x) {
#if __has_builtin(__builtin_amdgcn_exp2f)
  return __builtin_amdgcn_exp2f(x);
#else
  return __expf(x * 0.6931471805599453f);
#endif
}
// T2 swizzle for 128B rows: XOR row-bits(0-2) into 16B-slot bits(4-6); involution
__device__ inline int swz128(int o) { return o ^ (((o >> 7) & 7) << 4); }

// ---------- f32 -> bf16 cast ----------
__global__ __launch_bounds__(256) void cast4_kernel(const float* __restrict__ in,
                                                    bf16* __restrict__ out, int n4) {
  int i = blockIdx.x * 256 + threadIdx.x;
  if (i >= n4) return;
  float4 v = reinterpret_cast<const float4*>(in)[i];
  ushort4 o;
  o.x = f2bf_bits(v.x); o.y = f2bf_bits(v.y); o.z = f2bf_bits(v.z); o.w = f2bf_bits(v.w);
  reinterpret_cast<ushort4*>(out)[i] = o;
}

// ---------- weight packing (concat rows, f32 -> bf16), K = 2048 ----------
__global__ __launch_bounds__(256) void pack_qkv_kernel(
    const float* __restrict__ wq, const float* __restrict__ wk, const float* __restrict__ wv,
    const float* __restrict__ lqA, const float* __restrict__ lkA, const float* __restrict__ lvA,
    const float* __restrict__ lqR, const float* __restrict__ lkR, const float* __restrict__ lvR,
    bf16* __restrict__ Wp) {
  int r = blockIdx.x;
  const float* src;
  if      (r < 2048) src = wq  + (size_t)r * 2048;
  else if (r < 2560) src = wk  + (size_t)(r - 2048) * 2048;
  else if (r < 3072) src = wv  + (size_t)(r - 2560) * 2048;
  else if (r < 3136) src = lqA + (size_t)(r - 3072) * 2048;
  else if (r < 3200) src = lkA + (size_t)(r - 3136) * 2048;
  else if (r < 3264) src = lvA + (size_t)(r - 3200) * 2048;
  else if (r < 3272) src = lqR + (size_t)(r - 3264) * 2048;
  else if (r < 3280) src = lkR + (size_t)(r - 3272) * 2048;
  else               src = lvR + (size_t)(r - 3280) * 2048;
  bf16* dst = Wp + (size_t)r * 2048;
  for (int c = threadIdx.x; c < 512; c += 256) {
    float4 v = reinterpret_cast<const float4*>(src)[c];
    ushort4 o;
    o.x = f2bf_bits(v.x); o.y = f2bf_bits(v.y); o.z = f2bf_bits(v.z); o.w = f2bf_bits(v.w);
    reinterpret_cast<ushort4*>(dst)[c] = o;
  }
}

__global__ __launch_bounds__(256) void pack_out_kernel(
    const float* __restrict__ wo, const float* __restrict__ loA,
    const float* __restrict__ loR, bf16* __restrict__ Wp) {
  int r = blockIdx.x;
  const float* src;
  if      (r < 2048) src = wo  + (size_t)r * 2048;
  else if (r < 2112) src = loA + (size_t)(r - 2048) * 2048;
  else               src = loR + (size_t)(r - 2112) * 2048;
  bf16* dst = Wp + (size_t)r * 2048;
  for (int c = threadIdx.x; c < 512; c += 256) {
    float4 v = reinterpret_cast<const float4*>(src)[c];
    ushort4 o;
    o.x = f2bf_bits(v.x); o.y = f2bf_bits(v.y); o.z = f2bf_bits(v.z); o.w = f2bf_bits(v.w);
    reinterpret_cast<ushort4*>(dst)[c] = o;
  }
}

// ---------- LoRA-B transpose-pack: Bt[col][er] bf16, cols = q|k|v|o ----------
__global__ __launch_bounds__(256) void pack_bt_kernel(
    const float* __restrict__ lqB, const float* __restrict__ lkB,
    const float* __restrict__ lvB, const float* __restrict__ loB,
    bf16* __restrict__ Bt) {
  int idx = blockIdx.x * 256 + threadIdx.x;   // 5120 cols * 8 e-chunks
  int col = idx >> 3, e = idx & 7;
  const float* src; int o, OUT;
  if (col < 2048)      { src = lqB; o = col;        OUT = 2048; }
  else if (col < 2560) { src = lkB; o = col - 2048; OUT = 512; }
  else if (col < 3072) { src = lvB; o = col - 2560; OUT = 512; }
  else                 { src = loB; o = col - 3072; OUT = 2048; }
  const float4* s4 = reinterpret_cast<const float4*>(src + ((size_t)e * OUT + o) * 8);
  float4 v0 = s4[0], v1 = s4[1];
  s16x8 p;
  p[0] = f2bf_bits(v0.x); p[1] = f2bf_bits(v0.y); p[2] = f2bf_bits(v0.z); p[3] = f2bf_bits(v0.w);
  p[4] = f2bf_bits(v1.x); p[5] = f2bf_bits(v1.y); p[6] = f2bf_bits(v1.z); p[7] = f2bf_bits(v1.w);
  *reinterpret_cast<s16x8*>(&Bt[(size_t)col * 64 + e * 8]) = p;
}

// ---------- bf16 MFMA GEMM v6: 128x128 tile, BK=64, 2-buffer, swizzled ----------
__device__ inline void gld_lds16(const void* g, void* l) {
  __builtin_amdgcn_global_load_lds((const __attribute__((address_space(1))) void*)g,
                                   (__attribute__((address_space(3))) void*)l, 16, 0, 0);
}

template <typename OT>
__global__ __launch_bounds__(256) void gemm_bt_kernel(
    const bf16* __restrict__ X, const bf16* __restrict__ W,
    OT* __restrict__ C, int M, int N, int K, int NX)
{
  __shared__ __align__(16) bf16 As[2][128 * 64];   // 16KB / buf
  __shared__ __align__(16) bf16 Bs[2][128 * 64];
  const int tid = threadIdx.x;
  const int lane = tid & 63;
  const int wid = tid >> 6;
  const int cpx = gridDim.x >> 3;
  const int wg = ((int)blockIdx.x & 7) * cpx + ((int)blockIdx.x >> 3);
  const int n0 = (wg % NX) * 128;
  const int m0 = (wg / NX) * 128;
  const int wm = (wid >> 1) * 64;
  const int wn = (wid & 1) * 64;

  f32x4 acc[4][4] = {};
  const int fr = lane & 15;
  const int g  = lane >> 4;

  const bf16* xa[4];
  const bf16* wa[4];
  int oo[4];
  #pragma unroll
  for (int c = 0; c < 4; ++c) {
    oo[c] = c * 4096 + tid * 16;
    int a = swz128(oo[c]);
    int row = a >> 7;
    int ke  = (a & 127) >> 1;
    xa[c] = X + (size_t)(m0 + row) * K + ke;
    int wr = n0 + row; if (wr > N - 1) wr = N - 1;
    wa[c] = W + (size_t)wr * K + ke;
  }

  auto stage = [&](int kt, int b) {
    #pragma unroll
    for (int c = 0; c < 4; ++c) {
      gld_lds16(xa[c] + kt, (char*)As[b] + oo[c]);
      gld_lds16(wa[c] + kt, (char*)Bs[b] + oo[c]);
    }
  };

  int roffA[4][2], roffB[4][2];
  #pragma unroll
  for (int i = 0; i < 4; ++i)
    #pragma unroll
    for (int kc = 0; kc < 2; ++kc) {
      roffA[i][kc] = swz128((wm + i * 16 + fr) * 128 + kc * 64 + g * 16);
      roffB[i][kc] = swz128((wn + i * 16 + fr) * 128 + kc * 64 + g * 16);
    }

  const int NT = K >> 6;
  stage(0, 0);
  __syncthreads();

  int cur = 0;
  for (int t = 0; t < NT; ++t) {
    if (t + 1 < NT) stage((t + 1) * 64, cur ^ 1);
    #pragma unroll
    for (int kc = 0; kc < 2; ++kc) {
      s16x8 af[4], bfr[4];
      #pragma unroll
      for (int i = 0; i < 4; ++i) {
        af[i]  = *reinterpret_cast<const s16x8*>((char*)As[cur] + roffA[i][kc]);
        bfr[i] = *reinterpret_cast<const s16x8*>((char*)Bs[cur] + roffB[i][kc]);
      }
      #pragma unroll
      for (int i = 0; i < 4; ++i)
        #pragma unroll
        for (int j = 0; j < 4; ++j)
          acc[i][j] = __builtin_amdgcn_mfma_f32_16x16x32_bf16(af[i], bfr[j], acc[i][j], 0, 0, 0);
    }
    __syncthreads();
    cur ^= 1;
  }

  const int cr = g * 4;
  const int cc = fr;
  #pragma unroll
  for (int i = 0; i < 4; ++i)
    #pragma unroll
    for (int j = 0; j < 4; ++j) {
      int gn = n0 + wn + j * 16 + cc;
      if (gn >= N) continue;
      #pragma unroll
      for (int r = 0; r < 4; ++r) {
        int gm = m0 + wm + i * 16 + cr + r;
        if constexpr (__is_same(OT, bf16))
          C[(size_t)gm * N + gn] = __float2bfloat16(acc[i][j][r]);
        else
          C[(size_t)gm * N + gn] = acc[i][j][r];
      }
    }
}

// ---------- QKV epilogue v3: MFMA rank-64 apply + RoPE, tiny LDS ----------
__global__ __launch_bounds__(256) void qkv_epilogue3_kernel(
    const bf16* __restrict__ C1, const float* __restrict__ fc, const float* __restrict__ fs,
    const bf16* __restrict__ Bt,
    bf16* __restrict__ Qb, bf16* __restrict__ Kb, bf16* __restrict__ Vb)
{
  __shared__ __align__(16) bf16 Gs[64][72];
  const int bx = blockIdx.x;
  const int r0 = blockIdx.y * 64;
  const int t  = threadIdx.x;
  const int lane = t & 63, wid = t >> 6;
  const int fr = lane & 15, g = lane >> 4;
  int seg, opc0, pitch, btbase;
  if (bx < 8)       { seg = 0; opc0 = bx * 256;        pitch = 2048; btbase = 0; }
  else if (bx < 10) { seg = 1; opc0 = (bx - 8) * 256;  pitch = 512;  btbase = 2048; }
  else              { seg = 2; opc0 = (bx - 10) * 256; pitch = 512;  btbase = 2560; }
  const unsigned short* C1u = reinterpret_cast<const unsigned short*>(C1);

  {
    int row = t >> 2, q4 = t & 3;
    size_t grow = (size_t)(r0 + row);
    const unsigned short* lp = C1u + grow * NQKV_ + 3264 + seg * 8;
    float l[8], mx = -1e30f;
    #pragma unroll
    for (int e = 0; e < 8; ++e) { l[e] = bfbits2f(lp[e]); mx = fmaxf(mx, l[e]); }
    float sum = 0.f;
    #pragma unroll
    for (int e = 0; e < 8; ++e) { l[e] = __expf(l[e] - mx); sum += l[e]; }
    float inv = 4.0f / sum;
    const s16x8 h0 = *reinterpret_cast<const s16x8*>(
        &C1u[grow * NQKV_ + 3072 + seg * 64 + q4 * 16]);
    const s16x8 h1 = *reinterpret_cast<const s16x8*>(
        &C1u[grow * NQKV_ + 3072 + seg * 64 + q4 * 16 + 8]);
    s16x8 g0, g1;
    #pragma unroll
    for (int j = 0; j < 8; ++j) {
      int e0 = (q4 * 16 + j) >> 3;
      int e1 = (q4 * 16 + 8 + j) >> 3;
      g0[j] = (short)f2bf_bits(l[e0] * inv * bfbits2f((unsigned short)h0[j]));
      g1[j] = (short)f2bf_bits(l[e1] * inv * bfbits2f((unsigned short)h1[j]));
    }
    *reinterpret_cast<s16x8*>(&Gs[row][q4 * 16])     = g0;
    *reinterpret_cast<s16x8*>(&Gs[row][q4 * 16 + 8]) = g1;
  }
  __syncthreads();

  const int wm = (wid >> 1) * 32;
  const int wn = (wid & 1) * 128;
  f32x4 acc[8][2] = {};
  const bf16* Btb = Bt + (size_t)btbase * 64;
  #pragma unroll
  for (int kc = 0; kc < 2; ++kc) {
    s16x8 bfrag[2];
    #pragma unroll
    for (int i = 0; i < 2; ++i)
      bfrag[i] = *reinterpret_cast<const s16x8*>(&Gs[wm + i * 16 + fr][kc * 32 + g * 8]);
    #pragma unroll
    for (int jc = 0; jc < 8; ++jc) {
      s16x8 afrag = *reinterpret_cast<const s16x8*>(
          &Btb[(size_t)(opc0 + wn + jc * 16 + fr) * 64 + kc * 32 + g * 8]);
      #pragma unroll
      for (int i = 0; i < 2; ++i)
        acc[jc][i] = __builtin_amdgcn_mfma_f32_16x16x32_bf16(afrag, bfrag[i], acc[jc][i], 0, 0, 0);
    }
  }

  bf16* dst = seg == 0 ? Qb : (seg == 1 ? Kb : Vb);
  #pragma unroll
  for (int jc = 0; jc < 8; ++jc) {
    int colL = wn + jc * 16 + g * 4;
    int opc  = opc0 + colL;
    #pragma unroll
    for (int i = 0; i < 2; ++i) {
      size_t grow = (size_t)(r0 + wm + i * 16 + fr);
      uint2 bse = *reinterpret_cast<const uint2*>(&C1u[grow * NQKV_ + bx * 256 + colL]);
      float v0 = bfbits2f((unsigned short)(bse.x & 0xffff)) + acc[jc][i][0];
      float v1 = bfbits2f((unsigned short)(bse.x >> 16))    + acc[jc][i][1];
      float v2 = bfbits2f((unsigned short)(bse.y & 0xffff)) + acc[jc][i][2];
      float v3 = bfbits2f((unsigned short)(bse.y >> 16))    + acc[jc][i][3];
      uint2 o;
      if (seg < 2) {
        int hd0 = (opc >> 1) & 31;
        float c0 = fc[grow * 32 + hd0],     s0 = fs[grow * 32 + hd0];
        float c1 = fc[grow * 32 + hd0 + 1], s1 = fs[grow * 32 + hd0 + 1];
        float sc = seg == 0 ? 0.18033688f : 1.0f;   // 0.125*log2(e) for Q
        o.x = (unsigned)f2bf_bits((v0 * c0 - v1 * s0) * sc)
            | ((unsigned)f2bf_bits((v0 * s0 + v1 * c0) * sc) << 16);
        o.y = (unsigned)f2bf_bits((v2 * c1 - v3 * s1) * sc)
            | ((unsigned)f2bf_bits((v2 * s1 + v3 * c1) * sc) << 16);
      } else {
        o.x = (unsigned)f2bf_bits(v0) | ((unsigned)f2bf_bits(v1) << 16);
        o.y = (unsigned)f2bf_bits(v2) | ((unsigned)f2bf_bits(v3) << 16);
      }
      *reinterpret_cast<uint2*>(&dst[grow * pitch + opc]) = o;
    }
  }
}

// ---------- output epilogue v4: bf16 C2 + MFMA rank-64 apply, f32 out ----------
__global__ __launch_bounds__(256) void out_epilogue4_kernel(
    const bf16* __restrict__ C2b, const bf16* __restrict__ Bt, float* __restrict__ out)
{
  __shared__ __align__(16) bf16 Gs[64][72];
  const int bx = blockIdx.x;            // 0..7
  const int r0 = blockIdx.y * 64;
  const int t  = threadIdx.x;
  const int lane = t & 63, wid = t >> 6;
  const int fr = lane & 15, g = lane >> 4;
  const int opc0 = bx * 256;
  const unsigned short* C2u = reinterpret_cast<const unsigned short*>(C2b);

  {
    int row = t >> 2, q4 = t & 3;
    size_t grow = (size_t)(r0 + row);
    const unsigned short* lp = C2u + grow * NOUT_ + 2112;
    float l[8], mx = -1e30f;
    #pragma unroll
    for (int e = 0; e < 8; ++e) { l[e] = bfbits2f(lp[e]); mx = fmaxf(mx, l[e]); }
    float sum = 0.f;
    #pragma unroll
    for (int e = 0; e < 8; ++e) { l[e] = __expf(l[e] - mx); sum += l[e]; }
    float inv = 4.0f / sum;
    const s16x8 h0 = *reinterpret_cast<const s16x8*>(&C2u[grow * NOUT_ + 2048 + q4 * 16]);
    const s16x8 h1 = *reinterpret_cast<const s16x8*>(&C2u[grow * NOUT_ + 2048 + q4 * 16 + 8]);
    s16x8 g0, g1;
    #pragma unroll
    for (int j = 0; j < 8; ++j) {
      int e0 = (q4 * 16 + j) >> 3;
      int e1 = (q4 * 16 + 8 + j) >> 3;
      g0[j] = (short)f2bf_bits(l[e0] * inv * bfbits2f((unsigned short)h0[j]));
      g1[j] = (short)f2bf_bits(l[e1] * inv * bfbits2f((unsigned short)h1[j]));
    }
    *reinterpret_cast<s16x8*>(&Gs[row][q4 * 16])     = g0;
    *reinterpret_cast<s16x8*>(&Gs[row][q4 * 16 + 8]) = g1;
  }
  __syncthreads();

  const int wm = (wid >> 1) * 32;
  const int wn = (wid & 1) * 128;
  f32x4 acc[8][2] = {};
  const bf16* Btb = Bt + (size_t)3072 * 64;
  #pragma unroll
  for (int kc = 0; kc < 2; ++kc) {
    s16x8 bfrag[2];
    #pragma unroll
    for (int i = 0; i < 2; ++i)
      bfrag[i] = *reinterpret_cast<const s16x8*>(&Gs[wm + i * 16 + fr][kc * 32 + g * 8]);
    #pragma unroll
    for (int jc = 0; jc < 8; ++jc) {
      s16x8 afrag = *reinterpret_cast<const s16x8*>(
          &Btb[(size_t)(opc0 + wn + jc * 16 + fr) * 64 + kc * 32 + g * 8]);
      #pragma unroll
      for (int i = 0; i < 2; ++i)
        acc[jc][i] = __builtin_amdgcn_mfma_f32_16x16x32_bf16(afrag, bfrag[i], acc[jc][i], 0, 0, 0);
    }
  }

  #pragma unroll
  for (int jc = 0; jc < 8; ++jc) {
    int colL = wn + jc * 16 + g * 4;
    int opc  = opc0 + colL;
    #pragma unroll
    for (int i = 0; i < 2; ++i) {
      size_t grow = (size_t)(r0 + wm + i * 16 + fr);
      uint2 bse = *reinterpret_cast<const uint2*>(&C2u[grow * NOUT_ + opc]);
      float4 o;
      o.x = bfbits2f((unsigned short)(bse.x & 0xffff)) + acc[jc][i][0];
      o.y = bfbits2f((unsigned short)(bse.x >> 16))    + acc[jc][i][1];
      o.z = bfbits2f((unsigned short)(bse.y & 0xffff)) + acc[jc][i][2];
      o.w = bfbits2f((unsigned short)(bse.y >> 16))    + acc[jc][i][3];
      *reinterpret_cast<float4*>(&out[grow * 2048 + opc]) = o;
    }
  }
}

// ---------- K fragment pack: Kp[((hk*128+tk)*2+kc)*512 + l*8] ----------
__global__ __launch_bounds__(256) void pack_kf_kernel(const bf16* __restrict__ Kb,
                                                      bf16* __restrict__ Kp) {
  int idx = blockIdx.x * 256 + threadIdx.x;   // 131072 lane-slots
  int l = idx & 63;
  int rest = idx >> 6;
  int kc = rest & 1;
  int tk = (rest >> 1) & 127;
  int hk = rest >> 8;
  int fr = l & 15, g = l >> 4;
  s16x8 v = *reinterpret_cast<const s16x8*>(
      &Kb[(size_t)(tk * 16 + fr) * KVD_ + hk * 64 + kc * 32 + g * 8]);
  *reinterpret_cast<s16x8*>(&Kp[(size_t)idx * 8]) = v;
}

// ---------- V fragment pack (transpose): Vp[((hk*32+t64)*8+kc*4+dt)*512 + l*8] ----------
__global__ __launch_bounds__(256) void vt3_kernel(const unsigned short* __restrict__ Vb,
                                                  unsigned short* __restrict__ Vp) {
  __shared__ unsigned short tile[64][72];
  const int hk  = blockIdx.x >> 5;
  const int t64 = blockIdx.x & 31;
  const int s0  = t64 * 64;
  const int t   = threadIdx.x;
  #pragma unroll
  for (int r = 0; r < 2; ++r) {
    int idx = r * 256 + t;
    int row = idx >> 3, cc = idx & 7;
    *reinterpret_cast<s16x8*>(&tile[row][cc * 8]) =
        *reinterpret_cast<const s16x8*>(&Vb[(size_t)(s0 + row) * KVD_ + hk * 64 + cc * 8]);
  }
  __syncthreads();
  #pragma unroll
  for (int r = 0; r < 2; ++r) {
    int jj = t * 2 + r;                 // 0..511 slot-lanes
    int frag = jj >> 6, l = jj & 63;
    int kc = frag >> 2, dt = frag & 3;
    int fr = l & 15, gg = l >> 4;
    s16x8 o;
    #pragma unroll
    for (int e = 0; e < 8; ++e)
      o[e] = (short)tile[kc * 32 + gg * 8 + e][dt * 16 + fr];
    *reinterpret_cast<s16x8*>(
        &Vp[(((size_t)hk * 32 + t64) * 8 + frag) * 512 + (size_t)l * 8]) = o;
  }
}

// ---------- MFMA flash attention v8: packed frags + 4-way KV split ----------
// slot s = bx>>5 (0..207), head h = bx&31.
// s<16: direct row-chunk j=s (q0<512), full range, normalized write.
// s>=16: j = 16 + (s-16)/4, quarter q = (s-16)&3; tiles [q*8, min((q+1)*8, T)).
// Quarter 0 writes unnormalized partial IN-PLACE into O (renormalized by merge);
// quarters 1..3 into Op1/Op2/Op3. Empty quarters write ml=(-1e30,0) only.
__global__ __launch_bounds__(64) void attn_mfma8_kernel(
    const bf16* __restrict__ Q,   // [S][2048], pre-scaled by 0.125*log2(e)
    const bf16* __restrict__ Kp,  // packed K frags
    const bf16* __restrict__ Vp,  // packed V^T frags
    bf16* __restrict__ O,         // [S][2048]; also quarter-0 partial dest
    bf16* __restrict__ Op1, bf16* __restrict__ Op2, bf16* __restrict__ Op3,
    float2* __restrict__ ml)
{
  __shared__ __align__(16) bf16 Pw[2048];     // 4KB
  const int lane = threadIdx.x;
  const int fr = lane & 15, g = lane >> 4;
  const int bx = blockIdx.x;
  const int s  = bx >> 5;
  const int h  = bx & 31, hk = h >> 2;
  int j, qq, t0, t1; bool partial;
  if (s < 16) {
    j = s; qq = 0; t0 = 0; t1 = (32 * j + 95) >> 6; partial = false;
  } else {
    j = 16 + ((s - 16) >> 2); qq = (s - 16) & 3;
    int T = (32 * j + 95) >> 6;
    t0 = qq * 8; t1 = min((qq + 1) * 8, T); partial = true;
  }
  const int q0 = j * 32;
  const int nomask = (q0 + 1) >> 6;

  s16x8 qf[2][2];
  #pragma unroll
  for (int i = 0; i < 2; ++i)
    #pragma unroll
    for (int kc = 0; kc < 2; ++kc)
      qf[i][kc] = *reinterpret_cast<const s16x8*>(
          Q + (size_t)(q0 + i * 16 + fr) * 2048 + h * 64 + kc * 32 + g * 8);

  f32x4 acc[4][2] = {};
  float m[2]    = {-1e30f, -1e30f};
  float lsum[2] = {0.f, 0.f};
  const bf16* Kph = Kp + (size_t)hk * 131072;
  const bf16* Vph = Vp + (size_t)hk * 131072;

  s16x8 kf[2][4];
  #pragma unroll
  for (int kc = 0; kc < 2; ++kc)
    #pragma unroll
    for (int kt = 0; kt < 4; ++kt)
      kf[kc][kt] = *reinterpret_cast<const s16x8*>(
          Kph + ((size_t)(t0 * 4 + kt) * 2 + kc) * 512 + lane * 8);

  for (int t = t0; t < t1; ++t) {
    const int k0 = t * 64;
    s16x8 vf[2][4];
    #pragma unroll
    for (int kc = 0; kc < 2; ++kc)
      #pragma unroll
      for (int dt = 0; dt < 4; ++dt)
        vf[kc][dt] = *reinterpret_cast<const s16x8*>(
            Vph + ((size_t)t * 8 + kc * 4 + dt) * 512 + lane * 8);

    f32x4 st[4][2] = {};
    __builtin_amdgcn_s_setprio(1);
    #pragma unroll
    for (int kc = 0; kc < 2; ++kc)
      #pragma unroll
      for (int kt = 0; kt < 4; ++kt)
        #pragma unroll
        for (int i = 0; i < 2; ++i)
          st[kt][i] = __builtin_amdgcn_mfma_f32_16x16x32_bf16(kf[kc][kt], qf[i][kc], st[kt][i], 0, 0, 0);
    __builtin_amdgcn_s_setprio(0);

    if (t + 1 < t1) {
      #pragma unroll
      for (int kc = 0; kc < 2; ++kc)
        #pragma unroll
        for (int kt = 0; kt < 4; ++kt)
          kf[kc][kt] = *reinterpret_cast<const s16x8*>(
              Kph + ((size_t)((t + 1) * 4 + kt) * 2 + kc) * 512 + lane * 8);
    }

    if (t >= nomask) {
      #pragma unroll
      for (int kt = 0; kt < 4; ++kt)
        #pragma unroll
        for (int i = 0; i < 2; ++i)
          #pragma unroll
          for (int r = 0; r < 4; ++r) {
            int key = k0 + kt * 16 + g * 4 + r;
            int q   = q0 + i * 16 + fr;
            if (key > q) st[kt][i][r] = -1e30f;
          }
    }

    #pragma unroll
    for (int i = 0; i < 2; ++i) {
      float tm = -1e30f;
      #pragma unroll
      for (int kt = 0; kt < 4; ++kt)
        #pragma unroll
        for (int r = 0; r < 4; ++r)
          tm = fmaxf(tm, st[kt][i][r]);
      tm = fmaxf(tm, __shfl_xor(tm, 16));
      tm = fmaxf(tm, __shfl_xor(tm, 32));
      float newm = m[i];
      if (!__all(tm <= m[i] + 8.f)) {
        newm = fmaxf(m[i], tm);
        float rs = fexp2(m[i] - newm);
        lsum[i] *= rs;
        #pragma unroll
        for (int dt = 0; dt < 4; ++dt)
          #pragma unroll
          for (int r = 0; r < 4; ++r)
            acc[dt][i][r] *= rs;
        m[i] = newm;
      }
      #pragma unroll
      for (int kt = 0; kt < 4; ++kt) {
        float p0 = fexp2(st[kt][i][0] - newm);
        float p1 = fexp2(st[kt][i][1] - newm);
        float p2 = fexp2(st[kt][i][2] - newm);
        float p3 = fexp2(st[kt][i][3] - newm);
        lsum[i] += (p0 + p1) + (p2 + p3);
        uint2 pw;
        pw.x = (unsigned)f2bf_bits(p0) | ((unsigned)f2bf_bits(p1) << 16);
        pw.y = (unsigned)f2bf_bits(p2) | ((unsigned)f2bf_bits(p3) << 16);
        bf16* pb = Pw + (((i * 2 + (kt >> 1)) * 64 +
                          ((kt & 1) * 2 + (g >> 1)) * 16 + fr) * 8) + (g & 1) * 4;
        *reinterpret_cast<uint2*>(pb) = pw;
      }
    }

    s16x8 pf[2][2];
    #pragma unroll
    for (int i = 0; i < 2; ++i)
      #pragma unroll
      for (int kc = 0; kc < 2; ++kc)
        pf[i][kc] = *reinterpret_cast<const s16x8*>(
            (char*)Pw + (((i * 2 + kc) * 64 + lane) * 16));
    __builtin_amdgcn_s_setprio(1);
    #pragma unroll
    for (int kc = 0; kc < 2; ++kc)
      #pragma unroll
      for (int dt = 0; dt < 4; ++dt)
        #pragma unroll
        for (int i = 0; i < 2; ++i)
          acc[dt][i] = __builtin_amdgcn_mfma_f32_16x16x32_bf16(vf[kc][dt], pf[i][kc], acc[dt][i], 0, 0, 0);
    __builtin_amdgcn_s_setprio(0);
  }

  #pragma unroll
  for (int i = 0; i < 2; ++i) {
    lsum[i] += __shfl_xor(lsum[i], 16);
    lsum[i] += __shfl_xor(lsum[i], 32);
  }

  if (!partial) {
    float inv0 = 1.f / lsum[0], inv1 = 1.f / lsum[1];
    #pragma unroll
    for (int i = 0; i < 2; ++i) {
      float inv = i ? inv1 : inv0;
      #pragma unroll
      for (int dt = 0; dt < 4; ++dt)
        #pragma unroll
        for (int r2 = 0; r2 < 2; ++r2) {
          unsigned o = (unsigned)f2bf_bits(acc[dt][i][2 * r2] * inv)
                     | ((unsigned)f2bf_bits(acc[dt][i][2 * r2 + 1] * inv) << 16);
          size_t off = (size_t)(q0 + i * 16 + fr) * 2048 + h * 64 + dt * 16 + g * 4 + 2 * r2;
          *reinterpret_cast<unsigned*>(O + off) = o;
        }
    }
  } else {
    if (t1 > t0) {
      bf16* Op; int rbase;
      if (qq == 0)      { Op = O;   rbase = q0; }
      else if (qq == 1) { Op = Op1; rbase = q0 - 512; }
      else if (qq == 2) { Op = Op2; rbase = q0 - 1024; }
      else              { Op = Op3; rbase = q0 - 1024; }
      #pragma unroll
      for (int i = 0; i < 2; ++i)
        #pragma unroll
        for (int dt = 0; dt < 4; ++dt)
          #pragma unroll
          for (int r2 = 0; r2 < 2; ++r2) {
            unsigned o = (unsigned)f2bf_bits(acc[dt][i][2 * r2])
                       | ((unsigned)f2bf_bits(acc[dt][i][2 * r2 + 1]) << 16);
            size_t off = (size_t)(rbase + i * 16 + fr) * 2048 + h * 64 + dt * 16 + g * 4 + 2 * r2;
            *reinterpret_cast<unsigned*>(Op + off) = o;
          }
    }
    if (g == 0) {
      #pragma unroll
      for (int i = 0; i < 2; ++i)
        ml[((size_t)qq * 32 + h) * 1536 + (q0 - 512) + i * 16 + fr] =
            make_float2(m[i], lsum[i]);
    }
  }
}

// ---------- split-KV merge v2: rows 512..2047, 2 or 4 partials ----------
__global__ __launch_bounds__(256) void attn_merge2_kernel(
    bf16* __restrict__ O, const bf16* __restrict__ Op1,
    const bf16* __restrict__ Op2, const bf16* __restrict__ Op3,
    const float2* __restrict__ ml)
{
  int idx = blockIdx.x * 256 + threadIdx.x;   // 1536*1024 col-pairs
  int cp  = idx & 1023;
  int r   = idx >> 10;                        // 0..1535; global row = 512 + r
  int c   = cp * 2;
  int h   = c >> 6;
  bool four = (r >= 512);
  float2 a0 = ml[(size_t)(0 * 32 + h) * 1536 + r];
  float2 a1 = ml[(size_t)(1 * 32 + h) * 1536 + r];
  float M = fmaxf(a0.x, a1.x);
  float2 a2 = make_float2(-1e30f, 0.f), a3 = make_float2(-1e30f, 0.f);
  if (four) {
    a2 = ml[(size_t)(2 * 32 + h) * 1536 + r];
    a3 = ml[(size_t)(3 * 32 + h) * 1536 + r];
    M = fmaxf(M, fmaxf(a2.x, a3.x));
  }
  float e0 = fexp2(a0.x - M), e1 = fexp2(a1.x - M);
  float e2 = four ? fexp2(a2.x - M) : 0.f;
  float e3 = four ? fexp2(a3.x - M) : 0.f;
  float invL = 1.f / (a0.y * e0 + a1.y * e1 + a2.y * e2 + a3.y * e3);
  size_t grow = (size_t)(512 + r);
  unsigned p0 = *reinterpret_cast<const unsigned*>(O   + grow * 2048 + c);
  unsigned p1 = *reinterpret_cast<const unsigned*>(Op1 + (size_t)r * 2048 + c);
  float o0 = bfbits2f((unsigned short)(p0 & 0xffff)) * e0 +
             bfbits2f((unsigned short)(p1 & 0xffff)) * e1;
  float o1 = bfbits2f((unsigned short)(p0 >> 16)) * e0 +
             bfbits2f((unsigned short)(p1 >> 16)) * e1;
  if (four) {
    unsigned p2 = *reinterpret_cast<const unsigned*>(Op2 + (size_t)(r - 512) * 2048 + c);
    unsigned p3 = *reinterpret_cast<const unsigned*>(Op3 + (size_t)(r - 512) * 2048 + c);
    o0 += bfbits2f((unsigned short)(p2 & 0xffff)) * e2 +
          bfbits2f((unsigned short)(p3 & 0xffff)) * e3;
    o1 += bfbits2f((unsigned short)(p2 >> 16)) * e2 +
          bfbits2f((unsigned short)(p3 >> 16)) * e3;
  }
  o0 *= invL; o1 *= invL;
  unsigned o = (unsigned)f2bf_bits(o0) | ((unsigned)f2bf_bits(o1) << 16);
  *reinterpret_cast<unsigned*>(O + grow * 2048 + c) = o;
}

extern "C" void kernel_launch(void* const* d_in, const int* in_sizes, int n_in,
                              void* d_out, int out_size, void* d_ws, size_t ws_size,
                              hipStream_t stream) {
  const float* x   = (const float*)d_in[0];
  const float* fc  = (const float*)d_in[3];
  const float* fs  = (const float*)d_in[4];
  const float* wq  = (const float*)d_in[5];
  const float* wk  = (const float*)d_in[6];
  const float* wv  = (const float*)d_in[7];
  const float* wo  = (const float*)d_in[8];
  const float* lqR = (const float*)d_in[9];
  const float* lqA = (const float*)d_in[10];
  const float* lqB = (const float*)d_in[11];
  const float* lkR = (const float*)d_in[12];
  const float* lkA = (const float*)d_in[13];
  const float* lkB = (const float*)d_in[14];
  const float* lvR = (const float*)d_in[15];
  const float* lvA = (const float*)d_in[16];
  const float* lvB = (const float*)d_in[17];
  const float* loR = (const float*)d_in[18];
  const float* loA = (const float*)d_in[19];
  const float* loB = (const float*)d_in[20];
  float* out = (float*)d_out;
  char* ws = (char*)d_ws;

  if (ws_size < 58000000u) return;

  // layout (bytes); lifetime notes ensure no alias is live simultaneously
  bf16* xb   = (bf16*)(ws + 0);            // 8 MB; dead after gemm1 -> AOb
  bf16* Wqkv = (bf16*)(ws + 8388608);      // 13.47 MB; dead after gemm1 -> Wout
  bf16* Qb   = (bf16*)(ws + 21856256);     // 8 MB; dead after attn
  bf16* Kb   = (bf16*)(ws + 30244864);     // 2 MB; dead after pack_kf
  bf16* Vb   = (bf16*)(ws + 32342016);     // 2 MB; dead after vt3
  bf16* Vp   = (bf16*)(ws + 34439168);     // 2 MB packed V frags
  bf16* C1   = (bf16*)(ws + 36536320);     // 13.47 MB; dead after qkv epilogue
  bf16* Op1  = (bf16*)(ws + 36536320);     // 6.29 MB (aliases dead C1)
  bf16* Op2  = (bf16*)(ws + 42827776);     // 4.19 MB (aliases dead C1)
  bf16* Op3  = (bf16*)(ws + 30244864);     // 4.19 MB (aliases dead Kb+Vb)
  bf16* Bt   = (bf16*)(ws + 50003968);     // 640 KB packed LoRA-B
  bf16* Kp   = (bf16*)(ws + 50659328);     // 2 MB packed K frags
  float2* ml = (float2*)(ws + 52762624);   // 1.57 MB
  bf16* C2b  = (bf16*)(ws + 21856256);     // 8.68 MB (aliases dead Qb + Op3 head; gemm2 runs after merge)
  bf16* AOb  = xb;
  bf16* Wout = Wqkv;

  cast4_kernel<<<dim3(S_ * D_ / 4 / 256), dim3(256), 0, stream>>>(x, xb, S_ * D_ / 4);
  pack_qkv_kernel<<<dim3(NQKV_), dim3(256), 0, stream>>>(wq, wk, wv, lqA, lkA, lvA,
                                                         lqR, lkR, lvR, Wqkv);
  pack_bt_kernel<<<dim3(160), dim3(256), 0, stream>>>(lqB, lkB, lvB, loB, Bt);
  gemm_bt_kernel<bf16><<<dim3(26 * 16), dim3(256), 0, stream>>>(
      xb, Wqkv, C1, S_, NQKV_, D_, 26);
  qkv_epilogue3_kernel<<<dim3(12, 32), dim3(256), 0, stream>>>(C1, fc, fs, Bt, Qb, Kb, Vb);
  pack_kf_kernel<<<dim3(512), dim3(256), 0, stream>>>(Kb, Kp);
  vt3_kernel<<<dim3(256), dim3(256), 0, stream>>>((const unsigned short*)Vb,
                                                  (unsigned short*)Vp);
  attn_mfma8_kernel<<<dim3(208 * 32), dim3(64), 0, stream>>>(Qb, Kp, Vp, AOb,
                                                             Op1, Op2, Op3, ml);
  attn_merge2_kernel<<<dim3(6144), dim3(256), 0, stream>>>(AOb, Op1, Op2, Op3, ml);
  pack_out_kernel<<<dim3(NOUT_), dim3(256), 0, stream>>>(wo, loA, loR, Wout);
  gemm_bt_kernel<bf16><<<dim3(17 * 16), dim3(256), 0, stream>>>(
      AOb, Wout, C2b, S_, NOUT_, D_, 17);
  out_epilogue4_kernel<<<dim3(8, 32), dim3(256), 0, stream>>>(C2b, Bt, out);
}

// Round 19
// 184.157 us; speedup vs baseline: 1.0321x; 1.0321x over previous
//
#include <hip/hip_runtime.h>
#include <hip/hip_bf16.h>

static constexpr int S_    = 2048;
static constexpr int D_    = 2048;
static constexpr int NH_   = 32;
static constexpr int NKVH_ = 8;
static constexpr int HD_   = 64;
static constexpr int KVD_  = NKVH_ * HD_;   // 512
static constexpr int NQKV_ = 3288;          // 2048 q + 512 k + 512 v + 192 H + 24 logits
static constexpr int NOUT_ = 2120;          // 2048 o + 64 H + 8 logits

using bf16 = __hip_bfloat16;
typedef __attribute__((ext_vector_type(4))) float f32x4;
typedef __attribute__((ext_vector_type(8))) short s16x8;

__device__ inline unsigned short f2bf_bits(float f) {
  bf16 h = __float2bfloat16(f);
  union { bf16 b; unsigned short u; } cv; cv.b = h; return cv.u;
}
__device__ inline float bfbits2f(unsigned short u) {
  union { unsigned u32; float f; } cv; cv.u32 = (unsigned)u << 16; return cv.f;
}
__device__ inline float fexp2(float x) {
#if __has_builtin(__builtin_amdgcn_exp2f)
  return __builtin_amdgcn_exp2f(x);
#else
  return __expf(x * 0.6931471805599453f);
#endif
}
// T2 swizzle for 128B rows: XOR row-bits(0-2) into 16B-slot bits(4-6); involution
__device__ inline int swz128(int o) { return o ^ (((o >> 7) & 7) << 4); }

// ---------- f32 -> bf16 cast ----------
__global__ __launch_bounds__(256) void cast4_kernel(const float* __restrict__ in,
                                                    bf16* __restrict__ out, int n4) {
  int i = blockIdx.x * 256 + threadIdx.x;
  if (i >= n4) return;
  float4 v = reinterpret_cast<const float4*>(in)[i];
  ushort4 o;
  o.x = f2bf_bits(v.x); o.y = f2bf_bits(v.y); o.z = f2bf_bits(v.z); o.w = f2bf_bits(v.w);
  reinterpret_cast<ushort4*>(out)[i] = o;
}

// ---------- weight packing (concat rows, f32 -> bf16), K = 2048 ----------
__global__ __launch_bounds__(256) void pack_qkv_kernel(
    const float* __restrict__ wq, const float* __restrict__ wk, const float* __restrict__ wv,
    const float* __restrict__ lqA, const float* __restrict__ lkA, const float* __restrict__ lvA,
    const float* __restrict__ lqR, const float* __restrict__ lkR, const float* __restrict__ lvR,
    bf16* __restrict__ Wp) {
  int r = blockIdx.x;
  const float* src;
  if      (r < 2048) src = wq  + (size_t)r * 2048;
  else if (r < 2560) src = wk  + (size_t)(r - 2048) * 2048;
  else if (r < 3072) src = wv  + (size_t)(r - 2560) * 2048;
  else if (r < 3136) src = lqA + (size_t)(r - 3072) * 2048;
  else if (r < 3200) src = lkA + (size_t)(r - 3136) * 2048;
  else if (r < 3264) src = lvA + (size_t)(r - 3200) * 2048;
  else if (r < 3272) src = lqR + (size_t)(r - 3264) * 2048;
  else if (r < 3280) src = lkR + (size_t)(r - 3272) * 2048;
  else               src = lvR + (size_t)(r - 3280) * 2048;
  bf16* dst = Wp + (size_t)r * 2048;
  for (int c = threadIdx.x; c < 512; c += 256) {
    float4 v = reinterpret_cast<const float4*>(src)[c];
    ushort4 o;
    o.x = f2bf_bits(v.x); o.y = f2bf_bits(v.y); o.z = f2bf_bits(v.z); o.w = f2bf_bits(v.w);
    reinterpret_cast<ushort4*>(dst)[c] = o;
  }
}

__global__ __launch_bounds__(256) void pack_out_kernel(
    const float* __restrict__ wo, const float* __restrict__ loA,
    const float* __restrict__ loR, bf16* __restrict__ Wp) {
  int r = blockIdx.x;
  const float* src;
  if      (r < 2048) src = wo  + (size_t)r * 2048;
  else if (r < 2112) src = loA + (size_t)(r - 2048) * 2048;
  else               src = loR + (size_t)(r - 2112) * 2048;
  bf16* dst = Wp + (size_t)r * 2048;
  for (int c = threadIdx.x; c < 512; c += 256) {
    float4 v = reinterpret_cast<const float4*>(src)[c];
    ushort4 o;
    o.x = f2bf_bits(v.x); o.y = f2bf_bits(v.y); o.z = f2bf_bits(v.z); o.w = f2bf_bits(v.w);
    reinterpret_cast<ushort4*>(dst)[c] = o;
  }
}

// ---------- LoRA-B transpose-pack: Bt[col][er] bf16, cols = q|k|v|o ----------
__global__ __launch_bounds__(256) void pack_bt_kernel(
    const float* __restrict__ lqB, const float* __restrict__ lkB,
    const float* __restrict__ lvB, const float* __restrict__ loB,
    bf16* __restrict__ Bt) {
  int idx = blockIdx.x * 256 + threadIdx.x;   // 5120 cols * 8 e-chunks
  int col = idx >> 3, e = idx & 7;
  const float* src; int o, OUT;
  if (col < 2048)      { src = lqB; o = col;        OUT = 2048; }
  else if (col < 2560) { src = lkB; o = col - 2048; OUT = 512; }
  else if (col < 3072) { src = lvB; o = col - 2560; OUT = 512; }
  else                 { src = loB; o = col - 3072; OUT = 2048; }
  const float4* s4 = reinterpret_cast<const float4*>(src + ((size_t)e * OUT + o) * 8);
  float4 v0 = s4[0], v1 = s4[1];
  s16x8 p;
  p[0] = f2bf_bits(v0.x); p[1] = f2bf_bits(v0.y); p[2] = f2bf_bits(v0.z); p[3] = f2bf_bits(v0.w);
  p[4] = f2bf_bits(v1.x); p[5] = f2bf_bits(v1.y); p[6] = f2bf_bits(v1.z); p[7] = f2bf_bits(v1.w);
  *reinterpret_cast<s16x8*>(&Bt[(size_t)col * 64 + e * 8]) = p;
}

// ---------- bf16 MFMA GEMM v6: 128x128 tile, BK=64, 2-buffer, swizzled ----------
__device__ inline void gld_lds16(const void* g, void* l) {
  __builtin_amdgcn_global_load_lds((const __attribute__((address_space(1))) void*)g,
                                   (__attribute__((address_space(3))) void*)l, 16, 0, 0);
}

template <typename OT>
__global__ __launch_bounds__(256) void gemm_bt_kernel(
    const bf16* __restrict__ X, const bf16* __restrict__ W,
    OT* __restrict__ C, int M, int N, int K, int NX)
{
  __shared__ __align__(16) bf16 As[2][128 * 64];   // 16KB / buf
  __shared__ __align__(16) bf16 Bs[2][128 * 64];
  const int tid = threadIdx.x;
  const int lane = tid & 63;
  const int wid = tid >> 6;
  const int cpx = gridDim.x >> 3;
  const int wg = ((int)blockIdx.x & 7) * cpx + ((int)blockIdx.x >> 3);
  const int n0 = (wg % NX) * 128;
  const int m0 = (wg / NX) * 128;
  const int wm = (wid >> 1) * 64;
  const int wn = (wid & 1) * 64;

  f32x4 acc[4][4] = {};
  const int fr = lane & 15;
  const int g  = lane >> 4;

  const bf16* xa[4];
  const bf16* wa[4];
  int oo[4];
  #pragma unroll
  for (int c = 0; c < 4; ++c) {
    oo[c] = c * 4096 + tid * 16;
    int a = swz128(oo[c]);
    int row = a >> 7;
    int ke  = (a & 127) >> 1;
    xa[c] = X + (size_t)(m0 + row) * K + ke;
    int wr = n0 + row; if (wr > N - 1) wr = N - 1;
    wa[c] = W + (size_t)wr * K + ke;
  }

  auto stage = [&](int kt, int b) {
    #pragma unroll
    for (int c = 0; c < 4; ++c) {
      gld_lds16(xa[c] + kt, (char*)As[b] + oo[c]);
      gld_lds16(wa[c] + kt, (char*)Bs[b] + oo[c]);
    }
  };

  int roffA[4][2], roffB[4][2];
  #pragma unroll
  for (int i = 0; i < 4; ++i)
    #pragma unroll
    for (int kc = 0; kc < 2; ++kc) {
      roffA[i][kc] = swz128((wm + i * 16 + fr) * 128 + kc * 64 + g * 16);
      roffB[i][kc] = swz128((wn + i * 16 + fr) * 128 + kc * 64 + g * 16);
    }

  const int NT = K >> 6;
  stage(0, 0);
  __syncthreads();

  int cur = 0;
  for (int t = 0; t < NT; ++t) {
    if (t + 1 < NT) stage((t + 1) * 64, cur ^ 1);
    #pragma unroll
    for (int kc = 0; kc < 2; ++kc) {
      s16x8 af[4], bfr[4];
      #pragma unroll
      for (int i = 0; i < 4; ++i) {
        af[i]  = *reinterpret_cast<const s16x8*>((char*)As[cur] + roffA[i][kc]);
        bfr[i] = *reinterpret_cast<const s16x8*>((char*)Bs[cur] + roffB[i][kc]);
      }
      #pragma unroll
      for (int i = 0; i < 4; ++i)
        #pragma unroll
        for (int j = 0; j < 4; ++j)
          acc[i][j] = __builtin_amdgcn_mfma_f32_16x16x32_bf16(af[i], bfr[j], acc[i][j], 0, 0, 0);
    }
    __syncthreads();
    cur ^= 1;
  }

  const int cr = g * 4;
  const int cc = fr;
  #pragma unroll
  for (int i = 0; i < 4; ++i)
    #pragma unroll
    for (int j = 0; j < 4; ++j) {
      int gn = n0 + wn + j * 16 + cc;
      if (gn >= N) continue;
      #pragma unroll
      for (int r = 0; r < 4; ++r) {
        int gm = m0 + wm + i * 16 + cr + r;
        if constexpr (__is_same(OT, bf16))
          C[(size_t)gm * N + gn] = __float2bfloat16(acc[i][j][r]);
        else
          C[(size_t)gm * N + gn] = acc[i][j][r];
      }
    }
}

// ---------- QKV epilogue v3: MFMA rank-64 apply + RoPE, tiny LDS ----------
__global__ __launch_bounds__(256) void qkv_epilogue3_kernel(
    const bf16* __restrict__ C1, const float* __restrict__ fc, const float* __restrict__ fs,
    const bf16* __restrict__ Bt,
    bf16* __restrict__ Qb, bf16* __restrict__ Kb, bf16* __restrict__ Vb)
{
  __shared__ __align__(16) bf16 Gs[64][72];
  const int bx = blockIdx.x;
  const int r0 = blockIdx.y * 64;
  const int t  = threadIdx.x;
  const int lane = t & 63, wid = t >> 6;
  const int fr = lane & 15, g = lane >> 4;
  int seg, opc0, pitch, btbase;
  if (bx < 8)       { seg = 0; opc0 = bx * 256;        pitch = 2048; btbase = 0; }
  else if (bx < 10) { seg = 1; opc0 = (bx - 8) * 256;  pitch = 512;  btbase = 2048; }
  else              { seg = 2; opc0 = (bx - 10) * 256; pitch = 512;  btbase = 2560; }
  const unsigned short* C1u = reinterpret_cast<const unsigned short*>(C1);

  {
    int row = t >> 2, q4 = t & 3;
    size_t grow = (size_t)(r0 + row);
    const unsigned short* lp = C1u + grow * NQKV_ + 3264 + seg * 8;
    float l[8], mx = -1e30f;
    #pragma unroll
    for (int e = 0; e < 8; ++e) { l[e] = bfbits2f(lp[e]); mx = fmaxf(mx, l[e]); }
    float sum = 0.f;
    #pragma unroll
    for (int e = 0; e < 8; ++e) { l[e] = __expf(l[e] - mx); sum += l[e]; }
    float inv = 4.0f / sum;
    const s16x8 h0 = *reinterpret_cast<const s16x8*>(
        &C1u[grow * NQKV_ + 3072 + seg * 64 + q4 * 16]);
    const s16x8 h1 = *reinterpret_cast<const s16x8*>(
        &C1u[grow * NQKV_ + 3072 + seg * 64 + q4 * 16 + 8]);
    s16x8 g0, g1;
    #pragma unroll
    for (int j = 0; j < 8; ++j) {
      int e0 = (q4 * 16 + j) >> 3;
      int e1 = (q4 * 16 + 8 + j) >> 3;
      g0[j] = (short)f2bf_bits(l[e0] * inv * bfbits2f((unsigned short)h0[j]));
      g1[j] = (short)f2bf_bits(l[e1] * inv * bfbits2f((unsigned short)h1[j]));
    }
    *reinterpret_cast<s16x8*>(&Gs[row][q4 * 16])     = g0;
    *reinterpret_cast<s16x8*>(&Gs[row][q4 * 16 + 8]) = g1;
  }
  __syncthreads();

  const int wm = (wid >> 1) * 32;
  const int wn = (wid & 1) * 128;
  f32x4 acc[8][2] = {};
  const bf16* Btb = Bt + (size_t)btbase * 64;
  #pragma unroll
  for (int kc = 0; kc < 2; ++kc) {
    s16x8 bfrag[2];
    #pragma unroll
    for (int i = 0; i < 2; ++i)
      bfrag[i] = *reinterpret_cast<const s16x8*>(&Gs[wm + i * 16 + fr][kc * 32 + g * 8]);
    #pragma unroll
    for (int jc = 0; jc < 8; ++jc) {
      s16x8 afrag = *reinterpret_cast<const s16x8*>(
          &Btb[(size_t)(opc0 + wn + jc * 16 + fr) * 64 + kc * 32 + g * 8]);
      #pragma unroll
      for (int i = 0; i < 2; ++i)
        acc[jc][i] = __builtin_amdgcn_mfma_f32_16x16x32_bf16(afrag, bfrag[i], acc[jc][i], 0, 0, 0);
    }
  }

  bf16* dst = seg == 0 ? Qb : (seg == 1 ? Kb : Vb);
  #pragma unroll
  for (int jc = 0; jc < 8; ++jc) {
    int colL = wn + jc * 16 + g * 4;
    int opc  = opc0 + colL;
    #pragma unroll
    for (int i = 0; i < 2; ++i) {
      size_t grow = (size_t)(r0 + wm + i * 16 + fr);
      uint2 bse = *reinterpret_cast<const uint2*>(&C1u[grow * NQKV_ + bx * 256 + colL]);
      float v0 = bfbits2f((unsigned short)(bse.x & 0xffff)) + acc[jc][i][0];
      float v1 = bfbits2f((unsigned short)(bse.x >> 16))    + acc[jc][i][1];
      float v2 = bfbits2f((unsigned short)(bse.y & 0xffff)) + acc[jc][i][2];
      float v3 = bfbits2f((unsigned short)(bse.y >> 16))    + acc[jc][i][3];
      uint2 o;
      if (seg < 2) {
        int hd0 = (opc >> 1) & 31;
        float c0 = fc[grow * 32 + hd0],     s0 = fs[grow * 32 + hd0];
        float c1 = fc[grow * 32 + hd0 + 1], s1 = fs[grow * 32 + hd0 + 1];
        float sc = seg == 0 ? 0.18033688f : 1.0f;   // 0.125*log2(e) for Q
        o.x = (unsigned)f2bf_bits((v0 * c0 - v1 * s0) * sc)
            | ((unsigned)f2bf_bits((v0 * s0 + v1 * c0) * sc) << 16);
        o.y = (unsigned)f2bf_bits((v2 * c1 - v3 * s1) * sc)
            | ((unsigned)f2bf_bits((v2 * s1 + v3 * c1) * sc) << 16);
      } else {
        o.x = (unsigned)f2bf_bits(v0) | ((unsigned)f2bf_bits(v1) << 16);
        o.y = (unsigned)f2bf_bits(v2) | ((unsigned)f2bf_bits(v3) << 16);
      }
      *reinterpret_cast<uint2*>(&dst[grow * pitch + opc]) = o;
    }
  }
}

// ---------- output epilogue v4: bf16 C2 + MFMA rank-64 apply, f32 out ----------
__global__ __launch_bounds__(256) void out_epilogue4_kernel(
    const bf16* __restrict__ C2b, const bf16* __restrict__ Bt, float* __restrict__ out)
{
  __shared__ __align__(16) bf16 Gs[64][72];
  const int bx = blockIdx.x;            // 0..7
  const int r0 = blockIdx.y * 64;
  const int t  = threadIdx.x;
  const int lane = t & 63, wid = t >> 6;
  const int fr = lane & 15, g = lane >> 4;
  const int opc0 = bx * 256;
  const unsigned short* C2u = reinterpret_cast<const unsigned short*>(C2b);

  {
    int row = t >> 2, q4 = t & 3;
    size_t grow = (size_t)(r0 + row);
    const unsigned short* lp = C2u + grow * NOUT_ + 2112;
    float l[8], mx = -1e30f;
    #pragma unroll
    for (int e = 0; e < 8; ++e) { l[e] = bfbits2f(lp[e]); mx = fmaxf(mx, l[e]); }
    float sum = 0.f;
    #pragma unroll
    for (int e = 0; e < 8; ++e) { l[e] = __expf(l[e] - mx); sum += l[e]; }
    float inv = 4.0f / sum;
    const s16x8 h0 = *reinterpret_cast<const s16x8*>(&C2u[grow * NOUT_ + 2048 + q4 * 16]);
    const s16x8 h1 = *reinterpret_cast<const s16x8*>(&C2u[grow * NOUT_ + 2048 + q4 * 16 + 8]);
    s16x8 g0, g1;
    #pragma unroll
    for (int j = 0; j < 8; ++j) {
      int e0 = (q4 * 16 + j) >> 3;
      int e1 = (q4 * 16 + 8 + j) >> 3;
      g0[j] = (short)f2bf_bits(l[e0] * inv * bfbits2f((unsigned short)h0[j]));
      g1[j] = (short)f2bf_bits(l[e1] * inv * bfbits2f((unsigned short)h1[j]));
    }
    *reinterpret_cast<s16x8*>(&Gs[row][q4 * 16])     = g0;
    *reinterpret_cast<s16x8*>(&Gs[row][q4 * 16 + 8]) = g1;
  }
  __syncthreads();

  const int wm = (wid >> 1) * 32;
  const int wn = (wid & 1) * 128;
  f32x4 acc[8][2] = {};
  const bf16* Btb = Bt + (size_t)3072 * 64;
  #pragma unroll
  for (int kc = 0; kc < 2; ++kc) {
    s16x8 bfrag[2];
    #pragma unroll
    for (int i = 0; i < 2; ++i)
      bfrag[i] = *reinterpret_cast<const s16x8*>(&Gs[wm + i * 16 + fr][kc * 32 + g * 8]);
    #pragma unroll
    for (int jc = 0; jc < 8; ++jc) {
      s16x8 afrag = *reinterpret_cast<const s16x8*>(
          &Btb[(size_t)(opc0 + wn + jc * 16 + fr) * 64 + kc * 32 + g * 8]);
      #pragma unroll
      for (int i = 0; i < 2; ++i)
        acc[jc][i] = __builtin_amdgcn_mfma_f32_16x16x32_bf16(afrag, bfrag[i], acc[jc][i], 0, 0, 0);
    }
  }

  #pragma unroll
  for (int jc = 0; jc < 8; ++jc) {
    int colL = wn + jc * 16 + g * 4;
    int opc  = opc0 + colL;
    #pragma unroll
    for (int i = 0; i < 2; ++i) {
      size_t grow = (size_t)(r0 + wm + i * 16 + fr);
      uint2 bse = *reinterpret_cast<const uint2*>(&C2u[grow * NOUT_ + opc]);
      float4 o;
      o.x = bfbits2f((unsigned short)(bse.x & 0xffff)) + acc[jc][i][0];
      o.y = bfbits2f((unsigned short)(bse.x >> 16))    + acc[jc][i][1];
      o.z = bfbits2f((unsigned short)(bse.y & 0xffff)) + acc[jc][i][2];
      o.w = bfbits2f((unsigned short)(bse.y >> 16))    + acc[jc][i][3];
      *reinterpret_cast<float4*>(&out[grow * 2048 + opc]) = o;
    }
  }
}

// ---------- K fragment pack: Kp[((hk*128+tk)*2+kc)*512 + l*8] ----------
__global__ __launch_bounds__(256) void pack_kf_kernel(const bf16* __restrict__ Kb,
                                                      bf16* __restrict__ Kp) {
  int idx = blockIdx.x * 256 + threadIdx.x;   // 131072 lane-slots
  int l = idx & 63;
  int rest = idx >> 6;
  int kc = rest & 1;
  int tk = (rest >> 1) & 127;
  int hk = rest >> 8;
  int fr = l & 15, g = l >> 4;
  s16x8 v = *reinterpret_cast<const s16x8*>(
      &Kb[(size_t)(tk * 16 + fr) * KVD_ + hk * 64 + kc * 32 + g * 8]);
  *reinterpret_cast<s16x8*>(&Kp[(size_t)idx * 8]) = v;
}

// ---------- V fragment pack (transpose): Vp[((hk*32+t64)*8+kc*4+dt)*512 + l*8] ----------
__global__ __launch_bounds__(256) void vt3_kernel(const unsigned short* __restrict__ Vb,
                                                  unsigned short* __restrict__ Vp) {
  __shared__ unsigned short tile[64][72];
  const int hk  = blockIdx.x >> 5;
  const int t64 = blockIdx.x & 31;
  const int s0  = t64 * 64;
  const int t   = threadIdx.x;
  #pragma unroll
  for (int r = 0; r < 2; ++r) {
    int idx = r * 256 + t;
    int row = idx >> 3, cc = idx & 7;
    *reinterpret_cast<s16x8*>(&tile[row][cc * 8]) =
        *reinterpret_cast<const s16x8*>(&Vb[(size_t)(s0 + row) * KVD_ + hk * 64 + cc * 8]);
  }
  __syncthreads();
  #pragma unroll
  for (int r = 0; r < 2; ++r) {
    int jj = t * 2 + r;                 // 0..511 slot-lanes
    int frag = jj >> 6, l = jj & 63;
    int kc = frag >> 2, dt = frag & 3;
    int fr = l & 15, gg = l >> 4;
    s16x8 o;
    #pragma unroll
    for (int e = 0; e < 8; ++e)
      o[e] = (short)tile[kc * 32 + gg * 8 + e][dt * 16 + fr];
    *reinterpret_cast<s16x8*>(
        &Vp[(((size_t)hk * 32 + t64) * 8 + frag) * 512 + (size_t)l * 8]) = o;
  }
}

// ---------- MFMA flash attention v7: packed frags + 2-way KV split for long rows ----------
__global__ __launch_bounds__(64) void attn_mfma7_kernel(
    const bf16* __restrict__ Q,   // [S][2048], pre-scaled by 0.125*log2(e)
    const bf16* __restrict__ Kp,  // packed K frags
    const bf16* __restrict__ Vp,  // packed V^T frags
    bf16* __restrict__ O,         // [S][2048]
    bf16* __restrict__ Op0, bf16* __restrict__ Op1, float2* __restrict__ ml)
{
  __shared__ __align__(16) bf16 Pw[2048];     // 4KB
  const int lane = threadIdx.x;
  const int fr = lane & 15, g = lane >> 4;
  const int bx = blockIdx.x;
  const int s  = bx >> 5;
  const int h  = bx & 31, hk = h >> 2;
  int j, t0, t1, half; bool partial;
  if (s < 32)      { j = 63 - s; t0 = 0;  t1 = 16;                partial = true;  half = 0; }
  else if (s < 64) { j = 95 - s; t0 = 16; t1 = (32 * j + 95) >> 6; partial = true;  half = 1; }
  else             { j = 95 - s; t0 = 0;  t1 = (32 * j + 95) >> 6; partial = false; half = 0; }
  const int q0 = j * 32;
  const int nomask = (q0 + 1) >> 6;

  s16x8 qf[2][2];
  #pragma unroll
  for (int i = 0; i < 2; ++i)
    #pragma unroll
    for (int kc = 0; kc < 2; ++kc)
      qf[i][kc] = *reinterpret_cast<const s16x8*>(
          Q + (size_t)(q0 + i * 16 + fr) * 2048 + h * 64 + kc * 32 + g * 8);

  f32x4 acc[4][2] = {};
  float m[2]    = {-1e30f, -1e30f};
  float lsum[2] = {0.f, 0.f};
  const bf16* Kph = Kp + (size_t)hk * 131072;
  const bf16* Vph = Vp + (size_t)hk * 131072;

  s16x8 kf[2][4];
  #pragma unroll
  for (int kc = 0; kc < 2; ++kc)
    #pragma unroll
    for (int kt = 0; kt < 4; ++kt)
      kf[kc][kt] = *reinterpret_cast<const s16x8*>(
          Kph + ((size_t)(t0 * 4 + kt) * 2 + kc) * 512 + lane * 8);

  for (int t = t0; t < t1; ++t) {
    const int k0 = t * 64;
    s16x8 vf[2][4];
    #pragma unroll
    for (int kc = 0; kc < 2; ++kc)
      #pragma unroll
      for (int dt = 0; dt < 4; ++dt)
        vf[kc][dt] = *reinterpret_cast<const s16x8*>(
            Vph + ((size_t)t * 8 + kc * 4 + dt) * 512 + lane * 8);

    f32x4 st[4][2] = {};
    __builtin_amdgcn_s_setprio(1);
    #pragma unroll
    for (int kc = 0; kc < 2; ++kc)
      #pragma unroll
      for (int kt = 0; kt < 4; ++kt)
        #pragma unroll
        for (int i = 0; i < 2; ++i)
          st[kt][i] = __builtin_amdgcn_mfma_f32_16x16x32_bf16(kf[kc][kt], qf[i][kc], st[kt][i], 0, 0, 0);
    __builtin_amdgcn_s_setprio(0);

    if (t + 1 < t1) {
      #pragma unroll
      for (int kc = 0; kc < 2; ++kc)
        #pragma unroll
        for (int kt = 0; kt < 4; ++kt)
          kf[kc][kt] = *reinterpret_cast<const s16x8*>(
              Kph + ((size_t)((t + 1) * 4 + kt) * 2 + kc) * 512 + lane * 8);
    }

    if (t >= nomask) {
      #pragma unroll
      for (int kt = 0; kt < 4; ++kt)
        #pragma unroll
        for (int i = 0; i < 2; ++i)
          #pragma unroll
          for (int r = 0; r < 4; ++r) {
            int key = k0 + kt * 16 + g * 4 + r;
            int q   = q0 + i * 16 + fr;
            if (key > q) st[kt][i][r] = -1e30f;
          }
    }

    #pragma unroll
    for (int i = 0; i < 2; ++i) {
      float tm = -1e30f;
      #pragma unroll
      for (int kt = 0; kt < 4; ++kt)
        #pragma unroll
        for (int r = 0; r < 4; ++r)
          tm = fmaxf(tm, st[kt][i][r]);
      tm = fmaxf(tm, __shfl_xor(tm, 16));
      tm = fmaxf(tm, __shfl_xor(tm, 32));
      float newm = m[i];
      if (!__all(tm <= m[i] + 8.f)) {
        newm = fmaxf(m[i], tm);
        float rs = fexp2(m[i] - newm);
        lsum[i] *= rs;
        #pragma unroll
        for (int dt = 0; dt < 4; ++dt)
          #pragma unroll
          for (int r = 0; r < 4; ++r)
            acc[dt][i][r] *= rs;
        m[i] = newm;
      }
      #pragma unroll
      for (int kt = 0; kt < 4; ++kt) {
        float p0 = fexp2(st[kt][i][0] - newm);
        float p1 = fexp2(st[kt][i][1] - newm);
        float p2 = fexp2(st[kt][i][2] - newm);
        float p3 = fexp2(st[kt][i][3] - newm);
        lsum[i] += (p0 + p1) + (p2 + p3);
        uint2 pw;
        pw.x = (unsigned)f2bf_bits(p0) | ((unsigned)f2bf_bits(p1) << 16);
        pw.y = (unsigned)f2bf_bits(p2) | ((unsigned)f2bf_bits(p3) << 16);
        bf16* pb = Pw + (((i * 2 + (kt >> 1)) * 64 +
                          ((kt & 1) * 2 + (g >> 1)) * 16 + fr) * 8) + (g & 1) * 4;
        *reinterpret_cast<uint2*>(pb) = pw;
      }
    }

    s16x8 pf[2][2];
    #pragma unroll
    for (int i = 0; i < 2; ++i)
      #pragma unroll
      for (int kc = 0; kc < 2; ++kc)
        pf[i][kc] = *reinterpret_cast<const s16x8*>(
            (char*)Pw + (((i * 2 + kc) * 64 + lane) * 16));
    __builtin_amdgcn_s_setprio(1);
    #pragma unroll
    for (int kc = 0; kc < 2; ++kc)
      #pragma unroll
      for (int dt = 0; dt < 4; ++dt)
        #pragma unroll
        for (int i = 0; i < 2; ++i)
          acc[dt][i] = __builtin_amdgcn_mfma_f32_16x16x32_bf16(vf[kc][dt], pf[i][kc], acc[dt][i], 0, 0, 0);
    __builtin_amdgcn_s_setprio(0);
  }

  #pragma unroll
  for (int i = 0; i < 2; ++i) {
    lsum[i] += __shfl_xor(lsum[i], 16);
    lsum[i] += __shfl_xor(lsum[i], 32);
  }

  if (!partial) {
    float inv0 = 1.f / lsum[0], inv1 = 1.f / lsum[1];
    #pragma unroll
    for (int i = 0; i < 2; ++i) {
      float inv = i ? inv1 : inv0;
      #pragma unroll
      for (int dt = 0; dt < 4; ++dt)
        #pragma unroll
        for (int r2 = 0; r2 < 2; ++r2) {
          unsigned o = (unsigned)f2bf_bits(acc[dt][i][2 * r2] * inv)
                     | ((unsigned)f2bf_bits(acc[dt][i][2 * r2 + 1] * inv) << 16);
          size_t off = (size_t)(q0 + i * 16 + fr) * 2048 + h * 64 + dt * 16 + g * 4 + 2 * r2;
          *reinterpret_cast<unsigned*>(O + off) = o;
        }
    }
  } else {
    bf16* Op = half ? Op1 : Op0;
    #pragma unroll
    for (int i = 0; i < 2; ++i) {
      #pragma unroll
      for (int dt = 0; dt < 4; ++dt)
        #pragma unroll
        for (int r2 = 0; r2 < 2; ++r2) {
          unsigned o = (unsigned)f2bf_bits(acc[dt][i][2 * r2])
                     | ((unsigned)f2bf_bits(acc[dt][i][2 * r2 + 1]) << 16);
          size_t off = (size_t)(q0 - 1024 + i * 16 + fr) * 2048 + h * 64 + dt * 16 + g * 4 + 2 * r2;
          *reinterpret_cast<unsigned*>(Op + off) = o;
        }
      if (g == 0)
        ml[((size_t)half * 32 + h) * 1024 + (q0 - 1024) + i * 16 + fr] =
            make_float2(m[i], lsum[i]);
    }
  }
}

// ---------- split-KV merge: rows 1024..2047 ----------
__global__ __launch_bounds__(256) void attn_merge_kernel(
    const bf16* __restrict__ Op0, const bf16* __restrict__ Op1,
    const float2* __restrict__ ml, bf16* __restrict__ O)
{
  int idx = blockIdx.x * 256 + threadIdx.x;   // 1,048,576 col-pairs
  int cp  = idx & 1023;
  int row = idx >> 10;
  int c   = cp * 2;
  int h   = c >> 6;
  float2 a = ml[(size_t)h * 1024 + row];            // half0
  float2 b = ml[(size_t)(32 + h) * 1024 + row];     // half1
  float M  = fmaxf(a.x, b.x);
  float e0 = fexp2(a.x - M), e1 = fexp2(b.x - M);
  float invL = 1.f / (a.y * e0 + b.y * e1);
  unsigned p0 = *reinterpret_cast<const unsigned*>(Op0 + (size_t)row * 2048 + c);
  unsigned p1 = *reinterpret_cast<const unsigned*>(Op1 + (size_t)row * 2048 + c);
  float o0 = (bfbits2f((unsigned short)(p0 & 0xffff)) * e0 +
              bfbits2f((unsigned short)(p1 & 0xffff)) * e1) * invL;
  float o1 = (bfbits2f((unsigned short)(p0 >> 16)) * e0 +
              bfbits2f((unsigned short)(p1 >> 16)) * e1) * invL;
  unsigned o = (unsigned)f2bf_bits(o0) | ((unsigned)f2bf_bits(o1) << 16);
  *reinterpret_cast<unsigned*>(O + (size_t)(1024 + row) * 2048 + c) = o;
}

extern "C" void kernel_launch(void* const* d_in, const int* in_sizes, int n_in,
                              void* d_out, int out_size, void* d_ws, size_t ws_size,
                              hipStream_t stream) {
  const float* x   = (const float*)d_in[0];
  const float* fc  = (const float*)d_in[3];
  const float* fs  = (const float*)d_in[4];
  const float* wq  = (const float*)d_in[5];
  const float* wk  = (const float*)d_in[6];
  const float* wv  = (const float*)d_in[7];
  const float* wo  = (const float*)d_in[8];
  const float* lqR = (const float*)d_in[9];
  const float* lqA = (const float*)d_in[10];
  const float* lqB = (const float*)d_in[11];
  const float* lkR = (const float*)d_in[12];
  const float* lkA = (const float*)d_in[13];
  const float* lkB = (const float*)d_in[14];
  const float* lvR = (const float*)d_in[15];
  const float* lvA = (const float*)d_in[16];
  const float* lvB = (const float*)d_in[17];
  const float* loR = (const float*)d_in[18];
  const float* loA = (const float*)d_in[19];
  const float* loB = (const float*)d_in[20];
  float* out = (float*)d_out;
  char* ws = (char*)d_ws;

  if (ws_size < 58000000u) return;

  bf16* xb   = (bf16*)(ws + 0);            // 8 MB; dead after gemm1 -> AOb
  bf16* Wqkv = (bf16*)(ws + 8388608);      // 13.47 MB; dead after gemm1 -> Wout
  bf16* Qb   = (bf16*)(ws + 21856256);     // 8 MB; dead after attn -> C2b
  bf16* Kb   = (bf16*)(ws + 30244864);     // 2 MB; dead after pack_kf
  bf16* Vb   = (bf16*)(ws + 32342016);     // 2 MB; dead after vt3
  bf16* Vp   = (bf16*)(ws + 34439168);     // 2 MB packed V frags
  bf16* C1   = (bf16*)(ws + 36536320);     // 13.47 MB; dead after qkv epilogue
  bf16* Op0  = (bf16*)(ws + 36536320);     // 4 MB partial O half0 (aliases dead C1)
  bf16* Op1  = (bf16*)(ws + 40730624);     // 4 MB partial O half1
  float2* ml = (float2*)(ws + 44924928);   // 512 KB per-row (m,l)
  bf16* Bt   = (bf16*)(ws + 50003968);     // 640 KB packed LoRA-B (q|k|v|o)
  bf16* Kp   = (bf16*)(ws + 50659328);     // 2 MB packed K frags
  bf16* C2b  = (bf16*)(ws + 21856256);     // 8.68 MB (aliases dead Qb; gemm2 after merge)
  bf16* AOb  = xb;
  bf16* Wout = Wqkv;

  cast4_kernel<<<dim3(S_ * D_ / 4 / 256), dim3(256), 0, stream>>>(x, xb, S_ * D_ / 4);
  pack_qkv_kernel<<<dim3(NQKV_), dim3(256), 0, stream>>>(wq, wk, wv, lqA, lkA, lvA,
                                                         lqR, lkR, lvR, Wqkv);
  pack_bt_kernel<<<dim3(160), dim3(256), 0, stream>>>(lqB, lkB, lvB, loB, Bt);
  gemm_bt_kernel<bf16><<<dim3(26 * 16), dim3(256), 0, stream>>>(
      xb, Wqkv, C1, S_, NQKV_, D_, 26);
  qkv_epilogue3_kernel<<<dim3(12, 32), dim3(256), 0, stream>>>(C1, fc, fs, Bt, Qb, Kb, Vb);
  pack_kf_kernel<<<dim3(512), dim3(256), 0, stream>>>(Kb, Kp);
  vt3_kernel<<<dim3(256), dim3(256), 0, stream>>>((const unsigned short*)Vb,
                                                  (unsigned short*)Vp);
  attn_mfma7_kernel<<<dim3(96 * 32), dim3(64), 0, stream>>>(Qb, Kp, Vp, AOb, Op0, Op1, ml);
  attn_merge_kernel<<<dim3(4096), dim3(256), 0, stream>>>(Op0, Op1, ml, AOb);
  pack_out_kernel<<<dim3(NOUT_), dim3(256), 0, stream>>>(wo, loA, loR, Wout);
  gemm_bt_kernel<bf16><<<dim3(17 * 16), dim3(256), 0, stream>>>(
      AOb, Wout, C2b, S_, NOUT_, D_, 17);
  out_epilogue4_kernel<<<dim3(8, 32), dim3(256), 0, stream>>>(C2b, Bt, out);
}